// Round 3
// baseline (1686.907 us; speedup 1.0000x reference)
//
#include <hip/hip_runtime.h>
#include <hip/hip_bf16.h>

#define NN 100000        // nodes per type (N_PLACE == N_TRANS == 100000)
#define NE 1000000       // edges per relation
#define FI 128
#define FO 64

// ---------------- projection + attention-logit kernel ----------------
// One wave per node: h[n,f] = sum_k x[n,k] W[k,f] + b[f]  (f = lane)
// al_j[n,head] = sum_d h[n,head*16+d] * a_j[head*16+d]
__global__ __launch_bounds__(256) void proj_kernel(
    const float* __restrict__ x, const float* __restrict__ W, const float* __restrict__ b,
    const float* __restrict__ a0, const float* __restrict__ a1,
    const float* __restrict__ a2, const float* __restrict__ a3,
    float* __restrict__ hout, float* __restrict__ al)
{
    __shared__ float Wl[FI * FO];
    for (int i = threadIdx.x; i < FI * FO; i += 256) Wl[i] = W[i];
    __syncthreads();

    const int lane = threadIdx.x & 63;
    const int wid  = threadIdx.x >> 6;
    const int gw   = blockIdx.x * 4 + wid;
    const int nw   = gridDim.x * 4;
    const int head = lane >> 4;

    const float bv  = b[lane];
    const float av0 = a0[lane];
    const float av1 = a1[lane];
    const float av2 = a2[lane];
    const float av3 = a3[lane];

    for (int n = gw; n < NN; n += nw) {
        const float x0 = x[n * FI + lane];
        const float x1 = x[n * FI + 64 + lane];
        float acc = bv;
#pragma unroll
        for (int k = 0; k < 64; ++k)
            acc = fmaf(__shfl(x0, k), Wl[k * FO + lane], acc);
#pragma unroll
        for (int k = 0; k < 64; ++k)
            acc = fmaf(__shfl(x1, k), Wl[(64 + k) * FO + lane], acc);

        hout[n * FO + lane] = acc;

        // head-wise dot with the 4 attention vectors (reduce within 16-lane groups)
        float p0 = acc * av0, p1 = acc * av1, p2 = acc * av2, p3 = acc * av3;
#pragma unroll
        for (int off = 1; off < 16; off <<= 1) {
            p0 += __shfl_xor(p0, off);
            p1 += __shfl_xor(p1, off);
            p2 += __shfl_xor(p2, off);
            p3 += __shfl_xor(p3, off);
        }
        if ((lane & 15) == 0) {
            al[0 * NN * 4 + n * 4 + head] = p0;
            al[1 * NN * 4 + n * 4 + head] = p1;
            al[2 * NN * 4 + n * 4 + head] = p2;
            al[3 * NN * 4 + n * 4 + head] = p3;
        }
    }
}

// ---------------- edge kernel: one wave per edge ----------------
// rel 0: pt (src place, dst trans)   -> out slot 0 (trans r0)
// rel 1: tt (src trans, dst trans)   -> out slot 1 (trans r1)
// rel 2: tp (src trans, dst place)   -> out slot 2 (place r0)
// rel 3: pp (src place, dst place)   -> out slot 3 (place r1)
// al layout per type: [0]=as roleA, [1]=as roleB, [2]=ad roleA, [3]=ad roleB
__global__ __launch_bounds__(256) void edge_kernel(
    const int* __restrict__ ei_pt, const int* __restrict__ ei_tt,
    const int* __restrict__ ei_tp, const int* __restrict__ ei_pp,
    const float* __restrict__ h_place, const float* __restrict__ h_trans,
    const float* __restrict__ al_place, const float* __restrict__ al_trans,
    float* __restrict__ outnum, float* __restrict__ ssum)
{
    const int rel = blockIdx.y;
    const int* ei; const float* hs; const float* als; const float* ald;
    if (rel == 0)      { ei = ei_pt; hs = h_place; als = al_place + 0 * NN * 4; ald = al_trans + 2 * NN * 4; }
    else if (rel == 1) { ei = ei_tt; hs = h_trans; als = al_trans + 1 * NN * 4; ald = al_trans + 3 * NN * 4; }
    else if (rel == 2) { ei = ei_tp; hs = h_trans; als = al_trans + 0 * NN * 4; ald = al_place + 2 * NN * 4; }
    else               { ei = ei_pp; hs = h_place; als = al_place + 1 * NN * 4; ald = al_place + 3 * NN * 4; }
    float* on = outnum + (size_t)rel * NN * FO;
    float* ss = ssum + (size_t)rel * NN * 4;

    const int lane = threadIdx.x & 63;
    const int head = lane >> 4;
    const int gw = (blockIdx.x * 256 + threadIdx.x) >> 6;
    const int nw = (gridDim.x * 256) >> 6;

    for (int e = gw; e < NE; e += nw) {
        const int src = ei[e];
        const int dst = ei[NE + e];
        float alpha = als[src * 4 + head] + ald[dst * 4 + head];
        alpha = alpha > 0.f ? alpha : 0.2f * alpha;
        const float ev = __expf(alpha);   // no max-subtraction needed: alpha is O(±4)
        const float hv = hs[src * FO + lane];
        unsafeAtomicAdd(&on[dst * FO + lane], hv * ev);
        if ((lane & 15) == 0) unsafeAtomicAdd(&ss[dst * 4 + head], ev);
    }
}

// ---------------- post: normalize + ReLU (in place) + tanh(out@kW+kb) partial mean ----------------
__global__ __launch_bounds__(256) void post_kernel(
    float* __restrict__ outnum, const float* __restrict__ ssum,
    const float* __restrict__ kW, const float* __restrict__ kb,
    float* __restrict__ mean_acc)
{
    const int type = blockIdx.y;           // 0 = place (rels 2,3), 1 = trans (rels 0,1)
    const int r0 = (type == 0) ? 2 : 0;
    const int r1 = r0 + 1;

    __shared__ float kWl[FO * FO];
    for (int i = threadIdx.x; i < FO * FO; i += 256) kWl[i] = kW[i];
    __syncthreads();

    const int lane = threadIdx.x & 63;
    const int wid  = threadIdx.x >> 6;
    const int head = lane >> 4;
    const float kbv = kb[lane];

    float* on0 = outnum + (size_t)r0 * NN * FO;
    float* on1 = outnum + (size_t)r1 * NN * FO;
    const float* ss0 = ssum + (size_t)r0 * NN * 4;
    const float* ss1 = ssum + (size_t)r1 * NN * 4;

    float ts0 = 0.f, ts1 = 0.f;
    const int gw = blockIdx.x * 4 + wid;
    const int nw = gridDim.x * 4;

    for (int n = gw; n < NN; n += nw) {
        float v0 = on0[n * FO + lane] / (ss0[n * 4 + head] + 1e-16f);
        float v1 = on1[n * FO + lane] / (ss1[n * 4 + head] + 1e-16f);
        v0 = fmaxf(v0, 0.f);
        v1 = fmaxf(v1, 0.f);
        on0[n * FO + lane] = v0;
        on1[n * FO + lane] = v1;

        float y0 = kbv, y1 = kbv;
#pragma unroll
        for (int k = 0; k < 64; ++k) {
            const float w = kWl[k * FO + lane];
            y0 = fmaf(__shfl(v0, k), w, y0);
            y1 = fmaf(__shfl(v1, k), w, y1);
        }
        ts0 += tanhf(y0);
        ts1 += tanhf(y1);
    }

    __shared__ float red[2][4][64];
    red[0][wid][lane] = ts0;
    red[1][wid][lane] = ts1;
    __syncthreads();
    if (wid == 0) {
        float s0 = red[0][0][lane] + red[0][1][lane] + red[0][2][lane] + red[0][3][lane];
        float s1 = red[1][0][lane] + red[1][1][lane] + red[1][2][lane] + red[1][3][lane];
        unsafeAtomicAdd(&mean_acc[r0 * 64 + lane], s0);
        unsafeAtomicAdd(&mean_acc[r1 * 64 + lane], s1);
    }
}

// ---------------- score: semantic attention weights ----------------
__global__ void score_kernel(const float* __restrict__ mean_acc, const float* __restrict__ q,
                             float* __restrict__ attn)
{
    const int lane = threadIdx.x;  // 64 threads
    const float qv = q[lane];
    float sc[4];
#pragma unroll
    for (int r = 0; r < 4; ++r) {
        float p = qv * mean_acc[r * 64 + lane] * (1.0f / (float)NN);
#pragma unroll
        for (int off = 1; off < 64; off <<= 1) p += __shfl_xor(p, off);
        sc[r] = p;
    }
    if (lane == 0) {
        // trans group: rels 0,1 ; place group: rels 2,3
        float m = fmaxf(sc[0], sc[1]);
        float e0 = expf(sc[0] - m), e1 = expf(sc[1] - m);
        attn[0] = e0 / (e0 + e1);
        attn[1] = e1 / (e0 + e1);
        m = fmaxf(sc[2], sc[3]);
        float f0 = expf(sc[2] - m), f1 = expf(sc[3] - m);
        attn[2] = f0 / (f0 + f1);
        attn[3] = f1 / (f0 + f1);
    }
}

// ---------------- combine: out = attn0*out_r0 + attn1*out_r1 (float32 output!) ----------------
__global__ __launch_bounds__(256) void combine_kernel(
    const float* __restrict__ outnum, const float* __restrict__ attn, float* __restrict__ out)
{
    const int type = blockIdx.y;           // 0 = place -> d_out[0:], 1 = trans -> d_out[NN*FO:]
    const int r0 = (type == 0) ? 2 : 0;
    const float a0 = attn[r0], a1 = attn[r0 + 1];
    const float4* o0 = (const float4*)(outnum + (size_t)r0 * NN * FO);
    const float4* o1 = (const float4*)(outnum + (size_t)(r0 + 1) * NN * FO);
    float4* dst = (float4*)(out + (size_t)type * NN * FO);
    const int n4 = NN * FO / 4;
    const int stride = gridDim.x * 256;
    for (int i = blockIdx.x * 256 + threadIdx.x; i < n4; i += stride) {
        const float4 u = o0[i];
        const float4 w = o1[i];
        float4 r;
        r.x = a0 * u.x + a1 * w.x;
        r.y = a0 * u.y + a1 * w.y;
        r.z = a0 * u.z + a1 * w.z;
        r.w = a0 * u.w + a1 * w.w;
        dst[i] = r;
    }
}

extern "C" void kernel_launch(void* const* d_in, const int* in_sizes, int n_in,
                              void* d_out, int out_size, void* d_ws, size_t ws_size,
                              hipStream_t stream)
{
    const float* x_place = (const float*)d_in[0];
    const float* x_trans = (const float*)d_in[1];
    const float* W_place = (const float*)d_in[2];
    const float* b_place = (const float*)d_in[3];
    const float* W_trans = (const float*)d_in[4];
    const float* b_trans = (const float*)d_in[5];
    const float* as_pt = (const float*)d_in[6];
    const float* ad_pt = (const float*)d_in[7];
    const float* as_tp = (const float*)d_in[8];
    const float* ad_tp = (const float*)d_in[9];
    const float* as_pp = (const float*)d_in[10];
    const float* ad_pp = (const float*)d_in[11];
    const float* as_tt = (const float*)d_in[12];
    const float* ad_tt = (const float*)d_in[13];
    const float* q  = (const float*)d_in[14];
    const float* kW = (const float*)d_in[15];
    const float* kb = (const float*)d_in[16];
    const int* ei_pt = (const int*)d_in[17];
    const int* ei_tp = (const int*)d_in[18];
    const int* ei_pp = (const int*)d_in[19];
    const int* ei_tt = (const int*)d_in[20];

    // ---- workspace layout ----
    char* ws = (char*)d_ws;
    float* h_place = (float*)ws;                                  // NN*64 f32 = 25.6 MB
    float* h_trans = h_place + (size_t)NN * FO;                   // 25.6 MB
    float* al_place = h_trans + (size_t)NN * FO;                  // 4*NN*4 f32 = 6.4 MB
    float* al_trans = al_place + 4 * (size_t)NN * 4;              // 6.4 MB
    float* outnum = al_trans + 4 * (size_t)NN * 4;                // 4*NN*64 f32 = 102.4 MB
    float* ssum = outnum + 4 * (size_t)NN * FO;                   // 4*NN*4 f32 = 6.4 MB
    float* mean_acc = ssum + 4 * (size_t)NN * 4;                  // 4*64 f32
    float* attn = mean_acc + 256;                                 // 4 f32

    // zero the atomic accumulators (contiguous region: outnum..attn)
    const size_t zero_bytes = (4 * (size_t)NN * FO + 4 * (size_t)NN * 4 + 256 + 4) * sizeof(float);
    hipMemsetAsync(outnum, 0, zero_bytes, stream);

    // place node roles: src of pt, src of pp, dst of tp, dst of pp
    proj_kernel<<<2048, 256, 0, stream>>>(x_place, W_place, b_place,
                                          as_pt, as_pp, ad_tp, ad_pp,
                                          h_place, al_place);
    // trans node roles: src of tp, src of tt, dst of pt, dst of tt
    proj_kernel<<<2048, 256, 0, stream>>>(x_trans, W_trans, b_trans,
                                          as_tp, as_tt, ad_pt, ad_tt,
                                          h_trans, al_trans);

    edge_kernel<<<dim3(4096, 4), 256, 0, stream>>>(ei_pt, ei_tt, ei_tp, ei_pp,
                                                   h_place, h_trans, al_place, al_trans,
                                                   outnum, ssum);

    post_kernel<<<dim3(1024, 2), 256, 0, stream>>>(outnum, ssum, kW, kb, mean_acc);

    score_kernel<<<1, 64, 0, stream>>>(mean_acc, q, attn);

    combine_kernel<<<dim3(1024, 2), 256, 0, stream>>>(outnum, attn, (float*)d_out);
}

// Round 4
// 1406.211 us; speedup vs baseline: 1.1996x; 1.1996x over previous
//
#include <hip/hip_runtime.h>
#include <hip/hip_bf16.h>

#define NN 100000        // nodes per type
#define NE 1000000       // edges per relation
#define FI 128
#define FO 64

typedef unsigned short u16;

__device__ __forceinline__ float bf2f(u16 u) {
    unsigned int v = ((unsigned int)u) << 16;
    return __uint_as_float(v);
}

// ---------------- projection + attention-logit kernel ----------------
// One wave per node: h[n,f] = sum_k x[n,k] W[k,f] + b[f]  (f = lane), h stored bf16
__global__ __launch_bounds__(256) void proj_kernel(
    const float* __restrict__ x, const float* __restrict__ W, const float* __restrict__ b,
    const float* __restrict__ a0, const float* __restrict__ a1,
    const float* __restrict__ a2, const float* __restrict__ a3,
    u16* __restrict__ hout, float* __restrict__ al)
{
    __shared__ float Wl[FI * FO];
    for (int i = threadIdx.x; i < FI * FO; i += 256) Wl[i] = W[i];
    __syncthreads();

    const int lane = threadIdx.x & 63;
    const int wid  = threadIdx.x >> 6;
    const int gw   = blockIdx.x * 4 + wid;
    const int nw   = gridDim.x * 4;
    const int head = lane >> 4;

    const float bv  = b[lane];
    const float av0 = a0[lane];
    const float av1 = a1[lane];
    const float av2 = a2[lane];
    const float av3 = a3[lane];

    for (int n = gw; n < NN; n += nw) {
        const float x0 = x[n * FI + lane];
        const float x1 = x[n * FI + 64 + lane];
        float acc = bv;
#pragma unroll
        for (int k = 0; k < 64; ++k)
            acc = fmaf(__shfl(x0, k), Wl[k * FO + lane], acc);
#pragma unroll
        for (int k = 0; k < 64; ++k)
            acc = fmaf(__shfl(x1, k), Wl[(64 + k) * FO + lane], acc);

        __hip_bfloat16 hv = __float2bfloat16(acc);
        hout[n * FO + lane] = *(u16*)&hv;

        float p0 = acc * av0, p1 = acc * av1, p2 = acc * av2, p3 = acc * av3;
#pragma unroll
        for (int off = 1; off < 16; off <<= 1) {
            p0 += __shfl_xor(p0, off);
            p1 += __shfl_xor(p1, off);
            p2 += __shfl_xor(p2, off);
            p3 += __shfl_xor(p3, off);
        }
        if ((lane & 15) == 0) {
            al[0 * NN * 4 + n * 4 + head] = p0;
            al[1 * NN * 4 + n * 4 + head] = p1;
            al[2 * NN * 4 + n * 4 + head] = p2;
            al[3 * NN * 4 + n * 4 + head] = p3;
        }
    }
}

// ---------------- CSR build: histogram ----------------
__global__ __launch_bounds__(256) void hist_kernel(
    const int* __restrict__ ei_pt, const int* __restrict__ ei_tt,
    const int* __restrict__ ei_tp, const int* __restrict__ ei_pp,
    int* __restrict__ counts)
{
    const int rel = blockIdx.y;
    const int* ei = (rel == 0) ? ei_pt : (rel == 1) ? ei_tt : (rel == 2) ? ei_tp : ei_pp;
    int* cnt = counts + (size_t)rel * NN;
    const int stride = gridDim.x * 256;
    for (int e = blockIdx.x * 256 + threadIdx.x; e < NE; e += stride)
        atomicAdd(&cnt[ei[NE + e]], 1);
}

// ---------------- CSR build: exclusive scan (one block per relation) ----------------
__global__ __launch_bounds__(1024) void scan_kernel(
    const int* __restrict__ counts, int* __restrict__ offs, int* __restrict__ cursor)
{
    const int rel = blockIdx.x;
    const int* cnt = counts + (size_t)rel * NN;
    int* of = offs + (size_t)rel * (NN + 1);
    int* cu = cursor + (size_t)rel * NN;
    __shared__ int sm[1024];
    const int tid = threadIdx.x;
    int running = 0;
    const int NCH = (NN + 4095) / 4096;
    for (int ch = 0; ch < NCH; ++ch) {
        const int idx = ch * 4096 + tid * 4;
        int4 c = make_int4(0, 0, 0, 0);
        if (idx < NN) c = *(const int4*)(cnt + idx);
        const int s = c.x + c.y + c.z + c.w;
        __syncthreads();
        sm[tid] = s;
        __syncthreads();
        for (int off = 1; off < 1024; off <<= 1) {
            int t = 0;
            if (tid >= off) t = sm[tid - off];
            __syncthreads();
            if (tid >= off) sm[tid] += t;
            __syncthreads();
        }
        const int excl = sm[tid] - s;
        const int total = sm[1023];
        if (idx < NN) {
            const int o0 = running + excl;
            of[idx]     = o0;             cu[idx]     = o0;
            of[idx + 1] = o0 + c.x;       cu[idx + 1] = o0 + c.x;
            of[idx + 2] = o0 + c.x + c.y; cu[idx + 2] = o0 + c.x + c.y;
            of[idx + 3] = o0 + c.x + c.y + c.z; cu[idx + 3] = o0 + c.x + c.y + c.z;
        }
        running += total;
    }
    if (tid == 0) of[NN] = running;
}

// ---------------- CSR build: scatter src into dst-bins ----------------
__global__ __launch_bounds__(256) void scatter_kernel(
    const int* __restrict__ ei_pt, const int* __restrict__ ei_tt,
    const int* __restrict__ ei_tp, const int* __restrict__ ei_pp,
    int* __restrict__ cursor, int* __restrict__ perm)
{
    const int rel = blockIdx.y;
    const int* ei = (rel == 0) ? ei_pt : (rel == 1) ? ei_tt : (rel == 2) ? ei_tp : ei_pp;
    int* cu = cursor + (size_t)rel * NN;
    int* pm = perm + (size_t)rel * NE;
    const int stride = gridDim.x * 256;
    for (int e = blockIdx.x * 256 + threadIdx.x; e < NE; e += stride) {
        const int src = ei[e];
        const int dst = ei[NE + e];
        const int pos = atomicAdd(&cu[dst], 1);
        pm[pos] = src;
    }
}

// ---------------- accumulate: wave per dst node, fused normalize+ReLU+semantic partial ----------------
// rel 0: pt -> trans r0 ; rel 1: tt -> trans r1 ; rel 2: tp -> place r0 ; rel 3: pp -> place r1
__global__ __launch_bounds__(256) void acc_kernel(
    const u16* __restrict__ hb_place, const u16* __restrict__ hb_trans,
    const float* __restrict__ al_place, const float* __restrict__ al_trans,
    const int* __restrict__ offs, const int* __restrict__ perm,
    const float* __restrict__ kW, const float* __restrict__ kb,
    float* __restrict__ outbuf, float* __restrict__ mean_acc)
{
    const int rel = blockIdx.y;
    const u16* hb; const float* als; const float* ald;
    if (rel == 0)      { hb = hb_place; als = al_place + 0 * NN * 4; ald = al_trans + 2 * NN * 4; }
    else if (rel == 1) { hb = hb_trans; als = al_trans + 1 * NN * 4; ald = al_trans + 3 * NN * 4; }
    else if (rel == 2) { hb = hb_trans; als = al_trans + 0 * NN * 4; ald = al_place + 2 * NN * 4; }
    else               { hb = hb_place; als = al_place + 1 * NN * 4; ald = al_place + 3 * NN * 4; }
    const int* of = offs + (size_t)rel * (NN + 1);
    const int* pm = perm + (size_t)rel * NE;
    float* ob = outbuf + (size_t)rel * NN * FO;

    const int lane = threadIdx.x & 63;
    const int wid  = threadIdx.x >> 6;
    const int head = lane >> 4;

    // per-lane kW column (f = lane): kW[k][lane], k = 0..63
    float kwc[64];
#pragma unroll
    for (int k = 0; k < 64; ++k) kwc[k] = kW[k * FO + lane];
    const float kbv = kb[lane];

    float ts = 0.f;
    const int gw = blockIdx.x * 4 + wid;
    const int nw = gridDim.x * 4;
    for (int n = gw; n < NN; n += nw) {
        const int beg = of[n], end = of[n + 1];
        const float ad4 = ald[n * 4 + head];
        float num = 0.f, den = 0.f;
        int i = beg;
        for (; i + 1 < end; i += 2) {     // 2-way ILP on the gather chain
            const int s0 = pm[i], s1 = pm[i + 1];
            float a0 = als[s0 * 4 + head] + ad4;
            float a1 = als[s1 * 4 + head] + ad4;
            const float h0 = bf2f(hb[s0 * FO + lane]);
            const float h1 = bf2f(hb[s1 * FO + lane]);
            a0 = a0 > 0.f ? a0 : 0.2f * a0;
            a1 = a1 > 0.f ? a1 : 0.2f * a1;
            const float e0 = __expf(a0), e1 = __expf(a1);
            num = fmaf(h0, e0, num);
            num = fmaf(h1, e1, num);
            den += e0 + e1;
        }
        if (i < end) {
            const int s0 = pm[i];
            float a0 = als[s0 * 4 + head] + ad4;
            const float h0 = bf2f(hb[s0 * FO + lane]);
            a0 = a0 > 0.f ? a0 : 0.2f * a0;
            const float e0 = __expf(a0);
            num = fmaf(h0, e0, num);
            den += e0;
        }
        const float outv = fmaxf(num / (den + 1e-16f), 0.f);
        ob[(size_t)n * FO + lane] = outv;

        // fused semantic-attention partial: y = out_row @ kW + kb, ts += tanh(y)
        float y = kbv;
#pragma unroll
        for (int k = 0; k < 64; ++k) y = fmaf(__shfl(outv, k), kwc[k], y);
        ts += tanhf(y);
    }

    __shared__ float red[4][64];
    red[wid][lane] = ts;
    __syncthreads();
    if (wid == 0) {
        const float s = red[0][lane] + red[1][lane] + red[2][lane] + red[3][lane];
        unsafeAtomicAdd(&mean_acc[rel * 64 + lane], s);
    }
}

// ---------------- score: semantic attention weights ----------------
__global__ void score_kernel(const float* __restrict__ mean_acc, const float* __restrict__ q,
                             float* __restrict__ attn)
{
    const int lane = threadIdx.x;  // 64 threads
    const float qv = q[lane];
    float sc[4];
#pragma unroll
    for (int r = 0; r < 4; ++r) {
        float p = qv * mean_acc[r * 64 + lane] * (1.0f / (float)NN);
#pragma unroll
        for (int off = 1; off < 64; off <<= 1) p += __shfl_xor(p, off);
        sc[r] = p;
    }
    if (lane == 0) {
        float m = fmaxf(sc[0], sc[1]);
        float e0 = expf(sc[0] - m), e1 = expf(sc[1] - m);
        attn[0] = e0 / (e0 + e1);
        attn[1] = e1 / (e0 + e1);
        m = fmaxf(sc[2], sc[3]);
        float f0 = expf(sc[2] - m), f1 = expf(sc[3] - m);
        attn[2] = f0 / (f0 + f1);
        attn[3] = f1 / (f0 + f1);
    }
}

// ---------------- combine: out = attn0*out_r0 + attn1*out_r1 (float32 output) ----------------
__global__ __launch_bounds__(256) void combine_kernel(
    const float* __restrict__ outbuf, const float* __restrict__ attn, float* __restrict__ out)
{
    const int type = blockIdx.y;           // 0 = place (rels 2,3), 1 = trans (rels 0,1)
    const int r0 = (type == 0) ? 2 : 0;
    const float a0 = attn[r0], a1 = attn[r0 + 1];
    const float4* o0 = (const float4*)(outbuf + (size_t)r0 * NN * FO);
    const float4* o1 = (const float4*)(outbuf + (size_t)(r0 + 1) * NN * FO);
    float4* dst = (float4*)(out + (size_t)type * NN * FO);
    const int n4 = NN * FO / 4;
    const int stride = gridDim.x * 256;
    for (int i = blockIdx.x * 256 + threadIdx.x; i < n4; i += stride) {
        const float4 u = o0[i];
        const float4 w = o1[i];
        float4 r;
        r.x = a0 * u.x + a1 * w.x;
        r.y = a0 * u.y + a1 * w.y;
        r.z = a0 * u.z + a1 * w.z;
        r.w = a0 * u.w + a1 * w.w;
        dst[i] = r;
    }
}

extern "C" void kernel_launch(void* const* d_in, const int* in_sizes, int n_in,
                              void* d_out, int out_size, void* d_ws, size_t ws_size,
                              hipStream_t stream)
{
    const float* x_place = (const float*)d_in[0];
    const float* x_trans = (const float*)d_in[1];
    const float* W_place = (const float*)d_in[2];
    const float* b_place = (const float*)d_in[3];
    const float* W_trans = (const float*)d_in[4];
    const float* b_trans = (const float*)d_in[5];
    const float* as_pt = (const float*)d_in[6];
    const float* ad_pt = (const float*)d_in[7];
    const float* as_tp = (const float*)d_in[8];
    const float* ad_tp = (const float*)d_in[9];
    const float* as_pp = (const float*)d_in[10];
    const float* ad_pp = (const float*)d_in[11];
    const float* as_tt = (const float*)d_in[12];
    const float* ad_tt = (const float*)d_in[13];
    const float* q  = (const float*)d_in[14];
    const float* kW = (const float*)d_in[15];
    const float* kb = (const float*)d_in[16];
    const int* ei_pt = (const int*)d_in[17];
    const int* ei_tp = (const int*)d_in[18];
    const int* ei_pp = (const int*)d_in[19];
    const int* ei_tt = (const int*)d_in[20];

    // ---- workspace layout ----
    char* ws = (char*)d_ws;
    u16* hb_place = (u16*)ws;                                     // NN*64 bf16 = 12.8 MB
    u16* hb_trans = hb_place + (size_t)NN * FO;                   // 12.8 MB
    float* al_place = (float*)(hb_trans + (size_t)NN * FO);       // 4*NN*4 f32 = 6.4 MB
    float* al_trans = al_place + 4 * (size_t)NN * 4;              // 6.4 MB
    float* outbuf = al_trans + 4 * (size_t)NN * 4;                // 4*NN*64 f32 = 102.4 MB
    int* counts = (int*)(outbuf + 4 * (size_t)NN * FO);           // 4*NN int = 1.6 MB
    float* mean_acc = (float*)(counts + 4 * (size_t)NN);          // 256 f32
    float* attn = mean_acc + 256;                                 // 4 f32
    int* offs = (int*)(attn + 4);                                 // 4*(NN+1) int
    int* cursor = offs + 4 * (size_t)(NN + 1);                    // 4*NN int
    int* perm = cursor + 4 * (size_t)NN;                          // 4*NE int = 16 MB

    // zero counts + mean_acc (+attn) in one shot
    hipMemsetAsync(counts, 0, (4 * (size_t)NN + 256 + 4) * sizeof(int), stream);

    // place node roles: src of pt, src of pp, dst of tp, dst of pp
    proj_kernel<<<2048, 256, 0, stream>>>(x_place, W_place, b_place,
                                          as_pt, as_pp, ad_tp, ad_pp,
                                          hb_place, al_place);
    // trans node roles: src of tp, src of tt, dst of pt, dst of tt
    proj_kernel<<<2048, 256, 0, stream>>>(x_trans, W_trans, b_trans,
                                          as_tp, as_tt, ad_pt, ad_tt,
                                          hb_trans, al_trans);

    hist_kernel<<<dim3(1024, 4), 256, 0, stream>>>(ei_pt, ei_tt, ei_tp, ei_pp, counts);
    scan_kernel<<<4, 1024, 0, stream>>>(counts, offs, cursor);
    scatter_kernel<<<dim3(1024, 4), 256, 0, stream>>>(ei_pt, ei_tt, ei_tp, ei_pp, cursor, perm);

    acc_kernel<<<dim3(512, 4), 256, 0, stream>>>(hb_place, hb_trans, al_place, al_trans,
                                                 offs, perm, kW, kb, outbuf, mean_acc);

    score_kernel<<<1, 64, 0, stream>>>(mean_acc, q, attn);

    combine_kernel<<<dim3(1024, 2), 256, 0, stream>>>(outbuf, attn, (float*)d_out);
}